// Round 1
// baseline (1822.440 us; speedup 1.0000x reference)
//
#include <hip/hip_runtime.h>

#define N_NODES 100000
#define N_EDGES 1600000
#define SCAN_CHUNK 1024
#define SCAN_BLOCKS ((N_NODES + SCAN_CHUNK - 1) / SCAN_CHUNK)  // 98

typedef short short8 __attribute__((ext_vector_type(8)));
typedef float f32x4 __attribute__((ext_vector_type(4)));

__device__ __forceinline__ float bf2f(unsigned short u) {
    unsigned int x = ((unsigned int)u) << 16;
    float f; __builtin_memcpy(&f, &x, 4); return f;
}
__device__ __forceinline__ unsigned short f2bf(float f) {
    unsigned int x; __builtin_memcpy(&x, &f, 4);
    unsigned int r = x + 0x7fffu + ((x >> 16) & 1u);   // RNE
    return (unsigned short)(r >> 16);
}
__device__ __forceinline__ float sigmoidf(float x) {
    return 1.0f / (1.0f + __expf(-x));
}

// ---- counting sort machinery ---------------------------------------------

__global__ void count_k(const int* __restrict__ ei, int* __restrict__ cnt) {
    int e = blockIdx.x * 256 + threadIdx.x;
    if (e < N_EDGES) atomicAdd(&cnt[ei[e]], 1);
}

__global__ void scanA_k(const int* __restrict__ cnt, int* __restrict__ bsums) {
    __shared__ int sh[256];
    int b = blockIdx.x, t = threadIdx.x;
    int i0 = b * SCAN_CHUNK + t * 4;
    int s = 0;
    if (i0 + 3 < N_NODES) {
        int4 v = *(const int4*)(cnt + i0);
        s = v.x + v.y + v.z + v.w;
    } else {
        for (int j = 0; j < 4; ++j) if (i0 + j < N_NODES) s += cnt[i0 + j];
    }
    sh[t] = s; __syncthreads();
    for (int off = 128; off > 0; off >>= 1) {
        if (t < off) sh[t] += sh[t + off];
        __syncthreads();
    }
    if (t == 0) bsums[b] = sh[0];
}

__global__ void scanB_k(int* __restrict__ bsums, int* __restrict__ base) {
    if (threadIdx.x == 0 && blockIdx.x == 0) {
        int run = 0;
        for (int b = 0; b < SCAN_BLOCKS; ++b) { int v = bsums[b]; bsums[b] = run; run += v; }
        base[N_NODES] = run;  // == N_EDGES
    }
}

__global__ void scanC_k(const int* __restrict__ cnt, const int* __restrict__ bsums,
                        int* __restrict__ base) {
    __shared__ int sh[256];
    int b = blockIdx.x, t = threadIdx.x;
    int i0 = b * SCAN_CHUNK + t * 4;
    int c[4]; int s = 0;
    for (int j = 0; j < 4; ++j) {
        int idx = i0 + j;
        c[j] = (idx < N_NODES) ? cnt[idx] : 0;
        s += c[j];
    }
    sh[t] = s; __syncthreads();
    for (int off = 1; off < 256; off <<= 1) {
        int v = (t >= off) ? sh[t - off] : 0;
        __syncthreads();
        sh[t] += v;
        __syncthreads();
    }
    int excl = sh[t] - s + bsums[b];
    for (int j = 0; j < 4; ++j) {
        int idx = i0 + j;
        if (idx < N_NODES) { base[idx] = excl; excl += c[j]; }
    }
}

__global__ void bucket_k(const int* __restrict__ ei, const int* __restrict__ base,
                         int* __restrict__ cursor, int* __restrict__ seid,
                         int* __restrict__ sdst) {
    int e = blockIdx.x * 256 + threadIdx.x;
    if (e >= N_EDGES) return;
    int s = ei[e];
    int p = atomicAdd(&cursor[s], 1);
    int pos = base[s] + p;
    seid[pos] = e;
    sdst[pos] = ei[N_EDGES + e];
}

// ---- layer 1 aggregation: ms1 = 1 + 0.5*mean_{src} edge_attr --------------

__global__ void agg1_k(const float* __restrict__ ea, const int* __restrict__ seid,
                       const int* __restrict__ base, unsigned short* __restrict__ ms1) {
    int n = blockIdx.x * 4 + (threadIdx.x >> 6);
    int lane = threadIdx.x & 63;
    if (n >= N_NODES) return;
    int e0 = base[n], e1 = base[n + 1];
    float sx = 0.0f, sy = 0.0f;
    for (int eb = e0; eb < e1; eb += 64) {
        int cntb = e1 - eb; if (cntb > 64) cntb = 64;
        int myeid = (eb + lane < e1) ? seid[eb + lane] : 0;
        for (int i = 0; i < cntb; ++i) {
            int eid = __shfl(myeid, i);
            float2 v = ((const float2*)(ea + (size_t)eid * 128))[lane];
            sx += v.x; sy += v.y;
        }
    }
    int cnt = e1 - e0;
    float inv = (cnt > 0) ? (1.0f / (float)cnt) : 0.0f;
    ushort2 st;
    st.x = f2bf(1.0f + 0.5f * sx * inv);
    st.y = f2bf(1.0f + 0.5f * sy * inv);
    ((ushort2*)(ms1 + (size_t)n * 128))[lane] = st;
}

// ---- layer 2 aggregation: ms2 = 1 + 0.25*emb1[n] + 0.25*mean emb1[dst] ----

__global__ void agg2_k(const unsigned short* __restrict__ emb1, const int* __restrict__ sdst,
                       const int* __restrict__ base, unsigned short* __restrict__ ms2) {
    int n = blockIdx.x * 4 + (threadIdx.x >> 6);
    int lane = threadIdx.x & 63;
    if (n >= N_NODES) return;
    int e0 = base[n], e1 = base[n + 1];
    float sx = 0.0f, sy = 0.0f;
    for (int eb = e0; eb < e1; eb += 64) {
        int cntb = e1 - eb; if (cntb > 64) cntb = 64;
        int mydst = (eb + lane < e1) ? sdst[eb + lane] : 0;
        for (int i = 0; i < cntb; ++i) {
            int d = __shfl(mydst, i);
            ushort2 u = ((const ushort2*)(emb1 + (size_t)d * 128))[lane];
            sx += bf2f(u.x); sy += bf2f(u.y);
        }
    }
    int cnt = e1 - e0;
    float msx, msy;
    if (cnt > 0) {
        ushort2 me = ((const ushort2*)(emb1 + (size_t)n * 128))[lane];
        float inv = 0.25f / (float)cnt;
        msx = 1.0f + 0.25f * bf2f(me.x) + sx * inv;
        msy = 1.0f + 0.25f * bf2f(me.y) + sy * inv;
    } else {
        msx = 1.0f; msy = 1.0f;
    }
    ushort2 st; st.x = f2bf(msx); st.y = f2bf(msy);
    ((ushort2*)(ms2 + (size_t)n * 128))[lane] = st;
}

// ---- weight prep: transpose + bf16 ----------------------------------------

__global__ void prep_k(const float* __restrict__ W1, const float* __restrict__ W2,
                       unsigned short* __restrict__ W1t, unsigned short* __restrict__ W2t) {
    int i = blockIdx.x * 256 + threadIdx.x;
    if (i < 128 * 128) {                       // W1t[n*128+k] = W1[k*128+n]
        int n = i >> 7, k = i & 127;
        W1t[i] = f2bf(W1[k * 128 + n]);
    }
    if (i < 128 * 64) {                        // W2t[n*128+k] = W2[k*64+n]
        int n = i >> 7, k = i & 127;
        W2t[i] = f2bf(W2[k * 64 + n]);
    }
}

// ---- MFMA GEMM + sigmoid: out = sigmoid(A[100k x 128] @ Wt^T + b) ---------
// A bf16 row-major (K=128); Wt bf16 [NOUT][128] (pre-transposed weights).
// Per-wave 16x16 tile: A-frag m=lane&15,k=quad*8+j ; B-frag n=lane&15,k=quad*8+j ;
// D: row=quad*4+r, col=lane&15.

template <int NOUT, bool OUT_BF16>
__global__ void gemm_sig_k(const unsigned short* __restrict__ A,
                           const unsigned short* __restrict__ Wt,
                           const float* __restrict__ bias, void* __restrict__ out) {
    constexpr int NT = NOUT / 16;
    int w = blockIdx.x * 4 + (threadIdx.x >> 6);
    int lane = threadIdx.x & 63;
    int mt = w / NT, nt = w % NT;
    if (mt * 16 >= N_NODES) return;
    int row = lane & 15, quad = lane >> 4;
    const short* a_ptr = (const short*)A + (size_t)(mt * 16 + row) * 128 + quad * 8;
    const short* b_ptr = (const short*)Wt + (size_t)(nt * 16 + row) * 128 + quad * 8;
    f32x4 acc = {0.0f, 0.0f, 0.0f, 0.0f};
#pragma unroll
    for (int kb = 0; kb < 4; ++kb) {
        short8 a = *(const short8*)(a_ptr + kb * 32);
        short8 b = *(const short8*)(b_ptr + kb * 32);
        acc = __builtin_amdgcn_mfma_f32_16x16x32_bf16(a, b, acc, 0, 0, 0);
    }
    int col = nt * 16 + row;
    float bcol = bias[col];
#pragma unroll
    for (int r = 0; r < 4; ++r) {
        int node = mt * 16 + quad * 4 + r;
        float v = sigmoidf(acc[r] + bcol);
        if (OUT_BF16)
            ((unsigned short*)out)[(size_t)node * NOUT + col] = f2bf(v);
        else
            ((float*)out)[(size_t)node * NOUT + col] = v;
    }
}

// ---- final: embeddings + logits -------------------------------------------

__global__ void final_k(const int* __restrict__ ei, const float* __restrict__ emb2,
                        const float* __restrict__ Wf, const float* __restrict__ bf_,
                        float* __restrict__ out) {
    int e = blockIdx.x * 4 + (threadIdx.x >> 6);
    int lane = threadIdx.x & 63;
    if (e >= N_EDGES) return;
    int s = ei[e];
    int d = ei[N_EDGES + e];
    float v = 0.5f * (emb2[(size_t)s * 64 + lane] + emb2[(size_t)d * 64 + lane]);
    out[(size_t)N_EDGES + (size_t)e * 64 + lane] = v;
    float t = v * Wf[lane];
#pragma unroll
    for (int m = 32; m >= 1; m >>= 1) t += __shfl_xor(t, m);
    if (lane == 0) out[e] = t + bf_[0];
}

// ---- launch ---------------------------------------------------------------

extern "C" void kernel_launch(void* const* d_in, const int* in_sizes, int n_in,
                              void* d_out, int out_size, void* d_ws, size_t ws_size,
                              hipStream_t stream) {
    const float* edge_attr = (const float*)d_in[0];
    const int*   ei        = (const int*)d_in[1];
    const float* W1        = (const float*)d_in[3];
    const float* b1        = (const float*)d_in[4];
    const float* W2        = (const float*)d_in[5];
    const float* b2        = (const float*)d_in[6];
    const float* Wf        = (const float*)d_in[7];
    const float* bf_       = (const float*)d_in[8];
    float* out = (float*)d_out;

    char* ws = (char*)d_ws;
    size_t off = 0;
    auto alloc = [&](size_t sz) -> void* {
        void* p = ws + off;
        off += (sz + 255) & ~(size_t)255;
        return p;
    };
    int* cnt    = (int*)alloc(N_NODES * 4);
    int* cursor = (int*)alloc(N_NODES * 4);
    int* base   = (int*)alloc((N_NODES + 1) * 4);
    int* bsums  = (int*)alloc(SCAN_BLOCKS * 4);
    int* seid   = (int*)alloc(N_EDGES * 4);
    int* sdst   = (int*)alloc(N_EDGES * 4);
    unsigned short* ms   = (unsigned short*)alloc((size_t)N_NODES * 128 * 2); // ms1 then ms2
    unsigned short* emb1 = (unsigned short*)alloc((size_t)N_NODES * 128 * 2);
    float*          emb2 = (float*)alloc((size_t)N_NODES * 64 * 4);
    unsigned short* W1t  = (unsigned short*)alloc(128 * 128 * 2);
    unsigned short* W2t  = (unsigned short*)alloc(128 * 64 * 2);

    hipMemsetAsync(cnt, 0, N_NODES * 4, stream);
    hipMemsetAsync(cursor, 0, N_NODES * 4, stream);

    prep_k<<<64, 256, 0, stream>>>(W1, W2, W1t, W2t);
    count_k<<<N_EDGES / 256, 256, 0, stream>>>(ei, cnt);
    scanA_k<<<SCAN_BLOCKS, 256, 0, stream>>>(cnt, bsums);
    scanB_k<<<1, 64, 0, stream>>>(bsums, base);
    scanC_k<<<SCAN_BLOCKS, 256, 0, stream>>>(cnt, bsums, base);
    bucket_k<<<N_EDGES / 256, 256, 0, stream>>>(ei, base, cursor, seid, sdst);

    agg1_k<<<N_NODES / 4, 256, 0, stream>>>(edge_attr, seid, base, ms);
    gemm_sig_k<128, true><<<(N_NODES / 16) * 8 / 4, 256, 0, stream>>>(ms, W1t, b1, emb1);
    agg2_k<<<N_NODES / 4, 256, 0, stream>>>(emb1, sdst, base, ms);
    gemm_sig_k<64, false><<<(N_NODES / 16) * 4 / 4, 256, 0, stream>>>(ms, W2t, b2, emb2);
    final_k<<<N_EDGES / 4, 256, 0, stream>>>(ei, emb2, Wf, bf_, out);
}